// Round 3
// baseline (1881.807 us; speedup 1.0000x reference)
//
#include <hip/hip_runtime.h>
#include <hip/hip_bf16.h>

// Attention: B=2, H=16, S=2048, D=64. Inputs fp32, OUTPUT fp32 (reference
// returns float32; harness d_out is float* per contract). scale = 0.125.
//
// Round 2: SIMT fp32 flash attention, thread-per-query.
//   grid = 32 (b*h) x 32 q-blocks = 1024 blocks of 64 threads.
//   Per 32-key tile: stage K,V (fp32) into LDS, scores via broadcast
//   ds_read_b128, online softmax base-2, scores staged in LDS (stride 33,
//   conflict-free) to avoid dynamic reg indexing.

#define Bn 2
#define Hn 16
#define Sn 2048
#define Dn 64
#define QT 64   // queries per block == threads per block
#define KT 32   // keys per tile
#define NT (Sn / KT)

__device__ __forceinline__ float fast_exp2(float x) {
#if __has_builtin(__builtin_amdgcn_exp2f)
    return __builtin_amdgcn_exp2f(x);
#else
    return exp2f(x);
#endif
}

__global__ __launch_bounds__(QT)
void attn_fwd_simt(const float* __restrict__ Q,
                   const float* __restrict__ K,
                   const float* __restrict__ V,
                   float* __restrict__ O) {
    __shared__ float Ks[KT * Dn];
    __shared__ float Vs[KT * Dn];
    __shared__ float Sld[QT * (KT + 1)];

    const int tid = threadIdx.x;
    const int bh  = blockIdx.x >> 5;   // 0..31
    const int qb  = blockIdx.x & 31;   // 0..31
    const int row = qb * QT + tid;

    const float SCALE_LOG2E = 0.18033688011112042f;  // 0.125 * log2(e)

    const float* Qrow = Q + ((size_t)bh * Sn + row) * Dn;
    const float* Kbh  = K + (size_t)bh * Sn * Dn;
    const float* Vbh  = V + (size_t)bh * Sn * Dn;

    // ---- load this thread's query row into registers ----
    float4 q4[Dn / 4];
    {
        const float4* qsrc = (const float4*)Qrow;  // 16 x float4
        #pragma unroll
        for (int i = 0; i < 16; ++i) q4[i] = qsrc[i];
    }

    float4 o4[Dn / 4];
    #pragma unroll
    for (int i = 0; i < 16; ++i) o4[i] = make_float4(0.f, 0.f, 0.f, 0.f);
    float m = -1e30f;
    float l = 0.f;

    for (int t = 0; t < NT; ++t) {
        const int kt0 = t * KT;
        __syncthreads();  // prior tile's compute done before overwrite

        // ---- stage K,V tile: KT*Dn = 2048 floats = 512 float4 per tensor ----
        {
            const float4* ksrc = (const float4*)(Kbh + (size_t)kt0 * Dn);
            const float4* vsrc = (const float4*)(Vbh + (size_t)kt0 * Dn);
            #pragma unroll
            for (int r = 0; r < 8; ++r) {
                int idx = tid + 64 * r;        // 0..511, coalesced
                ((float4*)Ks)[idx] = ksrc[idx];
                ((float4*)Vs)[idx] = vsrc[idx];
            }
        }
        __syncthreads();

        // ---- scores: t_j = (q . k_j) * scale * log2(e) ----
        float tmax = -1e30f;
        #pragma unroll 4
        for (int j = 0; j < KT; ++j) {
            const float4* kk = (const float4*)(Ks + j * Dn);  // wave-uniform
            float a0 = 0.f, a1 = 0.f, a2 = 0.f, a3 = 0.f;
            #pragma unroll
            for (int d4 = 0; d4 < 16; d4 += 4) {
                float4 k0 = kk[d4 + 0], k1 = kk[d4 + 1];
                float4 k2 = kk[d4 + 2], k3 = kk[d4 + 3];
                float4 q0 = q4[d4 + 0], q1 = q4[d4 + 1];
                float4 q2 = q4[d4 + 2], q3 = q4[d4 + 3];
                a0 += q0.x * k0.x + q0.y * k0.y + q0.z * k0.z + q0.w * k0.w;
                a1 += q1.x * k1.x + q1.y * k1.y + q1.z * k1.z + q1.w * k1.w;
                a2 += q2.x * k2.x + q2.y * k2.y + q2.z * k2.z + q2.w * k2.w;
                a3 += q3.x * k3.x + q3.y * k3.y + q3.z * k3.z + q3.w * k3.w;
            }
            float s = ((a0 + a1) + (a2 + a3)) * SCALE_LOG2E;
            tmax = fmaxf(tmax, s);
            Sld[tid * (KT + 1) + j] = s;  // banks (tid+j)%32: 2-way, free
        }

        // ---- online softmax update ----
        float mnew  = fmaxf(m, tmax);
        float alpha = fast_exp2(m - mnew);
        m = mnew;
        l *= alpha;
        #pragma unroll
        for (int i = 0; i < 16; ++i) {
            o4[i].x *= alpha; o4[i].y *= alpha;
            o4[i].z *= alpha; o4[i].w *= alpha;
        }

        // ---- PV accumulation ----
        #pragma unroll 4
        for (int j = 0; j < KT; ++j) {
            float e = fast_exp2(Sld[tid * (KT + 1) + j] - mnew);
            l += e;
            const float4* vv = (const float4*)(Vs + j * Dn);  // wave-uniform
            #pragma unroll
            for (int d4 = 0; d4 < 16; ++d4) {
                float4 v = vv[d4];
                o4[d4].x = fmaf(e, v.x, o4[d4].x);
                o4[d4].y = fmaf(e, v.y, o4[d4].y);
                o4[d4].z = fmaf(e, v.z, o4[d4].z);
                o4[d4].w = fmaf(e, v.w, o4[d4].w);
            }
        }
    }

    // ---- epilogue: normalize and store fp32 ----
    float inv = 1.0f / l;
    float4* orow = (float4*)(O + ((size_t)bh * Sn + row) * Dn);
    #pragma unroll
    for (int i = 0; i < 16; ++i) {
        float4 f = o4[i];
        f.x *= inv; f.y *= inv; f.z *= inv; f.w *= inv;
        orow[i] = f;
    }
}

extern "C" void kernel_launch(void* const* d_in, const int* in_sizes, int n_in,
                              void* d_out, int out_size, void* d_ws, size_t ws_size,
                              hipStream_t stream) {
    const float* Q = (const float*)d_in[0];
    const float* K = (const float*)d_in[1];
    const float* V = (const float*)d_in[2];
    float* O = (float*)d_out;

    dim3 grid(Bn * Hn * (Sn / QT));  // 1024
    dim3 block(QT);                  // 64
    attn_fwd_simt<<<grid, block, 0, stream>>>(Q, K, V, O);
}

// Round 4
// 175.545 us; speedup vs baseline: 10.7198x; 10.7198x over previous
//
#include <hip/hip_runtime.h>
#include <hip/hip_bf16.h>

// Attention B=2,H=16,S=2048,D=64, fp32 in/out. Round 3: bf16 MFMA flash.
//
// Per block (256 thr = 4 waves): BM=128 q-rows (32/wave), key-tiles BN=64.
// S^T = K*Q^T via mfma_f32_32x32x16_bf16 (C/D: col=lane&31=qrow, row=key ->
// softmax = in-lane reduce + shfl_xor(32); m,l are per-lane scalars).
// PV as O^T = V^T * P^T: V staged transposed (bf16) in LDS; P^T round-trips
// through per-wave LDS (no barrier). Scale 0.125*log2e folded into Q cast.
// Epilogue: O^T -> LDS (overlay) -> coalesced float4 global stores.

#define Bn 2
#define Hn 16
#define Sn 2048
#define Dn 64
#define BM 128
#define BN 64
#define NT (Sn / BN)   // 32 key tiles
#define KP 72          // bf16 row pitch for K/Vt/Pt tiles (pad 8)
#define OP 68          // fp32 row pitch for epilogue buffer (pad 4)

typedef __attribute__((ext_vector_type(8)))  short s16x8;   // 8 bf16
typedef __attribute__((ext_vector_type(16))) float f32x16;  // 32x32 acc

__device__ __forceinline__ float fast_exp2(float x) {
#if __has_builtin(__builtin_amdgcn_exp2f)
    return __builtin_amdgcn_exp2f(x);
#else
    return exp2f(x);
#endif
}

__device__ __forceinline__ unsigned short f2bf(float f) {
    unsigned u = __float_as_uint(f);
    unsigned r = (u + 0x7fffu + ((u >> 16) & 1u)) >> 16;  // RNE
    return (unsigned short)r;
}
__device__ __forceinline__ unsigned pack2bf(float lo, float hi) {
    return (unsigned)f2bf(lo) | ((unsigned)f2bf(hi) << 16);
}
__device__ __forceinline__ s16x8 lds_frag(const unsigned short* p) {
    uint4 u = *(const uint4*)p;   // ds_read_b128 (16B-aligned by construction)
    return __builtin_bit_cast(s16x8, u);
}

__global__ __launch_bounds__(256, 2)
void attn_fwd_mfma(const float* __restrict__ Q,
                   const float* __restrict__ K,
                   const float* __restrict__ V,
                   float* __restrict__ O) {
    // LDS: KS 64*72*2=9216B | VT 64*72*2=9216B | PT 4*(32*72*2)=18432B = 36864B
    // Epilogue overlays with 4*(32*68*4)=34816B.
    __shared__ __align__(16) char smem[36864];
    unsigned short* KS = (unsigned short*)smem;
    unsigned short* VT = KS + 64 * KP;
    unsigned short* PT = VT + 64 * KP;

    const int tid  = threadIdx.x;
    const int wave = tid >> 6;
    const int lane = tid & 63;
    const int l31  = lane & 31;
    const int half = lane >> 5;

    const int bh = blockIdx.x >> 4;          // 0..31
    const int q0 = (blockIdx.x & 15) * BM;   // q-block origin

    const float* Qb = Q + (size_t)bh * Sn * Dn;
    const float* Kb = K + (size_t)bh * Sn * Dn;
    const float* Vb = V + (size_t)bh * Sn * Dn;

    const float FCT = 0.18033688011112042f;  // 0.125 * log2(e)

    // ---- Q fragments (B operand of S^T): lane holds Q[q0+wave*32+l31][d0..d0+7]
    s16x8 qf[4];
    {
        const float* qp = Qb + (size_t)(q0 + wave * 32 + l31) * Dn;
        #pragma unroll
        for (int ks = 0; ks < 4; ++ks) {
            const int d0 = ks * 16 + half * 8;
            float4 f0 = *(const float4*)(qp + d0);
            float4 f1 = *(const float4*)(qp + d0 + 4);
            uint4 u;
            u.x = pack2bf(f0.x * FCT, f0.y * FCT);
            u.y = pack2bf(f0.z * FCT, f0.w * FCT);
            u.z = pack2bf(f1.x * FCT, f1.y * FCT);
            u.w = pack2bf(f1.z * FCT, f1.w * FCT);
            qf[ks] = __builtin_bit_cast(s16x8, u);
        }
    }

    f32x16 accO0, accO1;
    #pragma unroll
    for (int r = 0; r < 16; ++r) { accO0[r] = 0.f; accO1[r] = 0.f; }
    float m = -1e30f, l = 0.f;

    // staging assignments
    const int skey = tid >> 2, sdc = tid & 3;   // K: key row, 16-d chunk
    const int vkey = tid & 63, vdg = tid >> 6;  // V: key row, 16-d chunk

    unsigned short* ptw = PT + (wave * 32 + l31) * KP;  // this lane's Pt row

    for (int t = 0; t < NT; ++t) {
        __syncthreads();  // K/VT free to overwrite

        // ---- stage K tile [64 keys][64 d] -> bf16 row-major ----
        {
            const float* kp = Kb + (size_t)(t * BN + skey) * Dn + sdc * 16;
            unsigned short* dst = KS + skey * KP + sdc * 16;
            #pragma unroll
            for (int i = 0; i < 4; ++i) {
                float4 f = *(const float4*)(kp + 4 * i);
                uint2 w;
                w.x = pack2bf(f.x, f.y);
                w.y = pack2bf(f.z, f.w);
                *(uint2*)(dst + 4 * i) = w;  // 8B-aligned
            }
        }
        // ---- stage V tile transposed: VT[d][key] ----
        {
            const float* vp = Vb + (size_t)(t * BN + vkey) * Dn + vdg * 16;
            #pragma unroll
            for (int i = 0; i < 4; ++i) {
                float4 f = *(const float4*)(vp + 4 * i);
                const int d0 = vdg * 16 + 4 * i;
                VT[(d0 + 0) * KP + vkey] = f2bf(f.x);
                VT[(d0 + 1) * KP + vkey] = f2bf(f.y);
                VT[(d0 + 2) * KP + vkey] = f2bf(f.z);
                VT[(d0 + 3) * KP + vkey] = f2bf(f.w);
            }
        }
        __syncthreads();

        // ---- S^T = K * Q^T  (two 32x32 key tiles) ----
        f32x16 s0, s1;
        #pragma unroll
        for (int r = 0; r < 16; ++r) { s0[r] = 0.f; s1[r] = 0.f; }
        #pragma unroll
        for (int ks = 0; ks < 4; ++ks) {
            const int off = ks * 16 + half * 8;
            s16x8 kf0 = lds_frag(KS + l31 * KP + off);
            s16x8 kf1 = lds_frag(KS + (32 + l31) * KP + off);
            s0 = __builtin_amdgcn_mfma_f32_32x32x16_bf16(kf0, qf[ks], s0, 0, 0, 0);
            s1 = __builtin_amdgcn_mfma_f32_32x32x16_bf16(kf1, qf[ks], s1, 0, 0, 0);
        }

        // ---- online softmax (per-lane row state; partner = lane^32) ----
        float mx = -1e30f;
        #pragma unroll
        for (int r = 0; r < 16; ++r) mx = fmaxf(mx, fmaxf(s0[r], s1[r]));
        mx = fmaxf(mx, __shfl_xor(mx, 32, 64));
        const float mn = fmaxf(m, mx);
        const float alpha = fast_exp2(m - mn);
        m = mn;
        float rs = 0.f;
        #pragma unroll
        for (int r = 0; r < 16; ++r) {
            s0[r] = fast_exp2(s0[r] - mn); rs += s0[r];
            s1[r] = fast_exp2(s1[r] - mn); rs += s1[r];
        }
        rs += __shfl_xor(rs, 32, 64);
        l = l * alpha + rs;
        #pragma unroll
        for (int r = 0; r < 16; ++r) { accO0[r] *= alpha; accO1[r] *= alpha; }

        // ---- P^T -> Pt[qrow][key] (wave-private; regs 4g..4g+3 = 4 consecutive keys)
        #pragma unroll
        for (int g = 0; g < 4; ++g) {
            uint2 w0, w1;
            w0.x = pack2bf(s0[4 * g + 0], s0[4 * g + 1]);
            w0.y = pack2bf(s0[4 * g + 2], s0[4 * g + 3]);
            w1.x = pack2bf(s1[4 * g + 0], s1[4 * g + 1]);
            w1.y = pack2bf(s1[4 * g + 2], s1[4 * g + 3]);
            *(uint2*)(ptw + 8 * g + 4 * half)      = w0;  // keys kt=0
            *(uint2*)(ptw + 8 * g + 4 * half + 32) = w1;  // keys kt=1
        }

        // ---- O^T += V^T * P^T ----
        #pragma unroll
        for (int ks = 0; ks < 4; ++ks) {
            const int off = ks * 16 + half * 8;
            s16x8 pf  = lds_frag(ptw + off);
            s16x8 vf0 = lds_frag(VT + l31 * KP + off);
            s16x8 vf1 = lds_frag(VT + (32 + l31) * KP + off);
            accO0 = __builtin_amdgcn_mfma_f32_32x32x16_bf16(vf0, pf, accO0, 0, 0, 0);
            accO1 = __builtin_amdgcn_mfma_f32_32x32x16_bf16(vf1, pf, accO1, 0, 0, 0);
        }
    }

    // ---- epilogue: normalize, transpose via LDS overlay, coalesced store ----
    __syncthreads();  // all waves done with KS/VT/PT
    const float inv = 1.0f / l;
    float* ob = (float*)smem + wave * 32 * OP;
    #pragma unroll
    for (int g = 0; g < 4; ++g) {
        const int d0 = 8 * g + 4 * half;
        float4 f0, f1;
        f0.x = accO0[4 * g + 0] * inv; f0.y = accO0[4 * g + 1] * inv;
        f0.z = accO0[4 * g + 2] * inv; f0.w = accO0[4 * g + 3] * inv;
        f1.x = accO1[4 * g + 0] * inv; f1.y = accO1[4 * g + 1] * inv;
        f1.z = accO1[4 * g + 2] * inv; f1.w = accO1[4 * g + 3] * inv;
        *(float4*)(ob + l31 * OP + d0)      = f0;  // d 0..31
        *(float4*)(ob + l31 * OP + d0 + 32) = f1;  // d 32..63
    }
    float* op = O + ((size_t)bh * Sn + q0 + wave * 32) * Dn;
    #pragma unroll
    for (int it = 0; it < 8; ++it) {
        const int idx = it * 64 + lane;     // 0..511
        const int r = idx >> 4, c = idx & 15;
        float4 f = *(float4*)(ob + r * OP + 4 * c);
        *(float4*)(op + r * Dn + 4 * c) = f;
    }
}

extern "C" void kernel_launch(void* const* d_in, const int* in_sizes, int n_in,
                              void* d_out, int out_size, void* d_ws, size_t ws_size,
                              hipStream_t stream) {
    const float* Q = (const float*)d_in[0];
    const float* K = (const float*)d_in[1];
    const float* V = (const float*)d_in[2];
    float* O = (float*)d_out;

    dim3 grid(Bn * Hn * (Sn / BM));  // 512
    dim3 block(256);
    attn_fwd_mfma<<<grid, block, 0, stream>>>(Q, K, V, O);
}

// Round 5
// 147.115 us; speedup vs baseline: 12.7914x; 1.1932x over previous
//
#include <hip/hip_runtime.h>
#include <hip/hip_bf16.h>

// Attention B=2,H=16,S=2048,D=64, fp32 in/out. Round 5: bf16 MFMA flash +
// pre-pass conversion.
//
// Pre-pass: K -> bf16 row-major Kb[bh][s][d]; V -> bf16 transposed
// Vt[bh][d][s] (LDS tile transpose). Q cast in-kernel (used once).
// Main (256 thr = 4 waves, BM=128 q, BN=64 keys/tile):
//   S^T = K*Q^T via mfma_f32_32x32x16_bf16 (C/D col=lane&31=qrow ->
//   softmax = in-lane reduce + shfl_xor(32)); P^T trunc-packed (v_perm)
//   to wave-private LDS; O^T = V^T*P^T; staging = pure b128 bf16 copies,
//   next tile's globals prefetched into regs during compute.
// Block swizzle: bh = blockIdx&31 so all 16 q-blocks of a bh share an XCD L2.

#define Bn 2
#define Hn 16
#define Sn 2048
#define Dn 64
#define BM 128
#define BN 64
#define NT (Sn / BN)   // 32 key tiles
#define KP 72          // bf16 row pitch for KS/VT/PT tiles (pad 8)
#define OP 68          // fp32 row pitch for epilogue buffer (pad 4)
#define TP 80          // prepass transpose pitch (16B-aligned rows)

typedef __attribute__((ext_vector_type(8)))  short s16x8;   // 8 bf16
typedef __attribute__((ext_vector_type(16))) float f32x16;  // 32x32 acc

__device__ __forceinline__ float fast_exp2(float x) {
#if __has_builtin(__builtin_amdgcn_exp2f)
    return __builtin_amdgcn_exp2f(x);
#else
    return exp2f(x);
#endif
}

__device__ __forceinline__ unsigned short f2bf(float f) {
    unsigned u = __float_as_uint(f);
    unsigned r = (u + 0x7fffu + ((u >> 16) & 1u)) >> 16;  // RNE
    return (unsigned short)r;
}
__device__ __forceinline__ unsigned pack2bf(float lo, float hi) {
    return (unsigned)f2bf(lo) | ((unsigned)f2bf(hi) << 16);
}
// truncation pack: 1 inst (v_perm_b32). P in [0,1]; <=0.4% rel err, fine.
__device__ __forceinline__ unsigned packtrunc(float lo, float hi) {
#if __has_builtin(__builtin_amdgcn_perm)
    return __builtin_amdgcn_perm(__float_as_uint(hi), __float_as_uint(lo),
                                 0x07060302u);
#else
    return (__float_as_uint(lo) >> 16) | (__float_as_uint(hi) & 0xffff0000u);
#endif
}
__device__ __forceinline__ s16x8 lds_frag(const unsigned short* p) {
    uint4 u = *(const uint4*)p;   // ds_read_b128 (16B-aligned by construction)
    return __builtin_bit_cast(s16x8, u);
}

// ---------------- pre-pass: K -> bf16, V -> bf16 transposed ----------------
__global__ __launch_bounds__(256)
void cast_kv(const float* __restrict__ K, const float* __restrict__ V,
             unsigned short* __restrict__ Kb, unsigned short* __restrict__ Vt) {
    __shared__ unsigned short T[64 * TP];
    const int tid = threadIdx.x;
    const int bh  = blockIdx.x >> 5;   // 0..31
    const int kb  = blockIdx.x & 31;   // key block of 64
    const int r = tid >> 2, c = (tid & 3) * 16;

    const size_t rowbase = ((size_t)bh * Sn + (size_t)kb * 64 + r) * Dn + c;
    {   // K: straight convert, coalesced
        const float* ks = K + rowbase;
        unsigned short* kd = Kb + rowbase;
        #pragma unroll
        for (int i = 0; i < 4; ++i) {
            float4 f = *(const float4*)(ks + 4 * i);
            uint2 w; w.x = pack2bf(f.x, f.y); w.y = pack2bf(f.z, f.w);
            *(uint2*)(kd + 4 * i) = w;
        }
    }
    {   // V: convert + transpose via LDS
        const float* vs = V + rowbase;
        #pragma unroll
        for (int i = 0; i < 4; ++i) {
            float4 f = *(const float4*)(vs + 4 * i);
            const int d0 = c + 4 * i;
            T[(d0 + 0) * TP + r] = f2bf(f.x);
            T[(d0 + 1) * TP + r] = f2bf(f.y);
            T[(d0 + 2) * TP + r] = f2bf(f.z);
            T[(d0 + 3) * TP + r] = f2bf(f.w);
        }
        __syncthreads();
        unsigned short* vd = Vt + ((size_t)bh * Dn + r) * Sn + (size_t)kb * 64 + c;
        *(uint4*)(vd)     = *(uint4*)(T + r * TP + c);
        *(uint4*)(vd + 8) = *(uint4*)(T + r * TP + c + 8);
    }
}

// ---------------- main flash kernel (bf16 pre-converted K/Vt) --------------
__global__ __launch_bounds__(256, 2)
void attn_fwd_mfma2(const float* __restrict__ Q,
                    const unsigned short* __restrict__ Kb,
                    const unsigned short* __restrict__ Vt,
                    float* __restrict__ O) {
    // KS 64*72*2=9216B | VT 64*72*2=9216B | PT 4*32*72*2=18432B = 36864B
    // epilogue overlays 4*(32*68*4)=34816B
    __shared__ __align__(16) char smem[36864];
    unsigned short* KS = (unsigned short*)smem;
    unsigned short* VT = KS + 64 * KP;
    unsigned short* PT = VT + 64 * KP;

    const int tid  = threadIdx.x;
    const int wave = tid >> 6;
    const int lane = tid & 63;
    const int l31  = lane & 31;
    const int half = lane >> 5;

    const int bh = blockIdx.x & 31;          // XCD-local: 16 q-blocks share L2
    const int q0 = (blockIdx.x >> 5) * BM;

    const float* Qb = Q + (size_t)bh * Sn * Dn;
    const unsigned short* Kbh = Kb + (size_t)bh * Sn * Dn;
    const unsigned short* Vbh = Vt + (size_t)bh * Dn * Sn;  // [d][s]

    const float FCT = 0.18033688011112042f;  // 0.125 * log2(e)

    // ---- Q fragments (B operand of S^T), scale folded, RNE ----
    s16x8 qf[4];
    {
        const float* qp = Qb + (size_t)(q0 + wave * 32 + l31) * Dn;
        #pragma unroll
        for (int ks = 0; ks < 4; ++ks) {
            const int d0 = ks * 16 + half * 8;
            float4 f0 = *(const float4*)(qp + d0);
            float4 f1 = *(const float4*)(qp + d0 + 4);
            uint4 u;
            u.x = pack2bf(f0.x * FCT, f0.y * FCT);
            u.y = pack2bf(f0.z * FCT, f0.w * FCT);
            u.z = pack2bf(f1.x * FCT, f1.y * FCT);
            u.w = pack2bf(f1.z * FCT, f1.w * FCT);
            qf[ks] = __builtin_bit_cast(s16x8, u);
        }
    }

    f32x16 accO0, accO1;
    #pragma unroll
    for (int r = 0; r < 16; ++r) { accO0[r] = 0.f; accO1[r] = 0.f; }
    float m = -1e30f, l = 0.f;

    // staging: thread -> (row kr, 16-col chunk kc); 32B per thread per tile
    const int kr = tid >> 2, kc = (tid & 3) * 16;
    const unsigned short* kg = Kbh + (size_t)kr * Dn + kc;  // + t*BN*Dn
    const unsigned short* vg = Vbh + (size_t)kr * Sn + kc;  // + t*BN

    uint4 krg0 = *(const uint4*)(kg);
    uint4 krg1 = *(const uint4*)(kg + 8);
    uint4 vrg0 = *(const uint4*)(vg);
    uint4 vrg1 = *(const uint4*)(vg + 8);

    unsigned short* ptw = PT + (wave * 32 + l31) * KP;  // lane's Pt row
    const unsigned short* kf0p = KS + l31 * KP;
    const unsigned short* kf1p = KS + (32 + l31) * KP;
    const unsigned short* vf0p = VT + l31 * KP;
    const unsigned short* vf1p = VT + (32 + l31) * KP;

    for (int t = 0; t < NT; ++t) {
        __syncthreads();  // prior tile's compute done
        *(uint4*)(KS + kr * KP + kc)     = krg0;
        *(uint4*)(KS + kr * KP + kc + 8) = krg1;
        *(uint4*)(VT + kr * KP + kc)     = vrg0;
        *(uint4*)(VT + kr * KP + kc + 8) = vrg1;
        __syncthreads();

        // prefetch next tile's globals (hidden under compute)
        {
            const int tn = (t + 1 < NT) ? t + 1 : t;
            const unsigned short* kgn = kg + (size_t)tn * BN * Dn;
            const unsigned short* vgn = vg + (size_t)tn * BN;
            krg0 = *(const uint4*)(kgn);
            krg1 = *(const uint4*)(kgn + 8);
            vrg0 = *(const uint4*)(vgn);
            vrg1 = *(const uint4*)(vgn + 8);
        }

        // ---- S^T = K * Q^T (two 32x32 key tiles) ----
        f32x16 s0, s1;
        #pragma unroll
        for (int r = 0; r < 16; ++r) { s0[r] = 0.f; s1[r] = 0.f; }
        #pragma unroll
        for (int ks = 0; ks < 4; ++ks) {
            const int off = ks * 16 + half * 8;
            s16x8 kf0 = lds_frag(kf0p + off);
            s16x8 kf1 = lds_frag(kf1p + off);
            s0 = __builtin_amdgcn_mfma_f32_32x32x16_bf16(kf0, qf[ks], s0, 0, 0, 0);
            s1 = __builtin_amdgcn_mfma_f32_32x32x16_bf16(kf1, qf[ks], s1, 0, 0, 0);
        }

        // ---- online softmax (per-lane row state; partner = lane^32) ----
        float mx = -1e30f;
        #pragma unroll
        for (int r = 0; r < 16; ++r) mx = fmaxf(mx, fmaxf(s0[r], s1[r]));
        mx = fmaxf(mx, __shfl_xor(mx, 32, 64));
        const float mn = fmaxf(m, mx);
        const float alpha = fast_exp2(m - mn);
        m = mn;
        float rs = 0.f;
        #pragma unroll
        for (int r = 0; r < 16; ++r) {
            s0[r] = fast_exp2(s0[r] - mn); rs += s0[r];
            s1[r] = fast_exp2(s1[r] - mn); rs += s1[r];
        }
        rs += __shfl_xor(rs, 32, 64);
        l = l * alpha + rs;
        #pragma unroll
        for (int r = 0; r < 16; ++r) { accO0[r] *= alpha; accO1[r] *= alpha; }

        // ---- P^T -> Pt[qrow][key] (wave-private; v_perm trunc pack) ----
        #pragma unroll
        for (int g = 0; g < 4; ++g) {
            uint2 w0, w1;
            w0.x = packtrunc(s0[4 * g + 0], s0[4 * g + 1]);
            w0.y = packtrunc(s0[4 * g + 2], s0[4 * g + 3]);
            w1.x = packtrunc(s1[4 * g + 0], s1[4 * g + 1]);
            w1.y = packtrunc(s1[4 * g + 2], s1[4 * g + 3]);
            *(uint2*)(ptw + 8 * g + 4 * half)      = w0;  // keys tile 0
            *(uint2*)(ptw + 8 * g + 4 * half + 32) = w1;  // keys tile 1
        }

        // ---- O^T += V^T * P^T ----
        #pragma unroll
        for (int ks = 0; ks < 4; ++ks) {
            const int off = ks * 16 + half * 8;
            s16x8 pf  = lds_frag(ptw + off);
            s16x8 vf0 = lds_frag(vf0p + off);
            s16x8 vf1 = lds_frag(vf1p + off);
            accO0 = __builtin_amdgcn_mfma_f32_32x32x16_bf16(vf0, pf, accO0, 0, 0, 0);
            accO1 = __builtin_amdgcn_mfma_f32_32x32x16_bf16(vf1, pf, accO1, 0, 0, 0);
        }
    }

    // ---- epilogue: normalize, transpose via LDS overlay, coalesced store ----
    __syncthreads();  // all waves done with KS/VT/PT
    const float inv = 1.0f / l;
    float* ob = (float*)smem + wave * 32 * OP;
    #pragma unroll
    for (int g = 0; g < 4; ++g) {
        const int d0 = 8 * g + 4 * half;
        float4 f0, f1;
        f0.x = accO0[4 * g + 0] * inv; f0.y = accO0[4 * g + 1] * inv;
        f0.z = accO0[4 * g + 2] * inv; f0.w = accO0[4 * g + 3] * inv;
        f1.x = accO1[4 * g + 0] * inv; f1.y = accO1[4 * g + 1] * inv;
        f1.z = accO1[4 * g + 2] * inv; f1.w = accO1[4 * g + 3] * inv;
        *(float4*)(ob + l31 * OP + d0)      = f0;  // d 0..31
        *(float4*)(ob + l31 * OP + d0 + 32) = f1;  // d 32..63
    }
    float* op = O + ((size_t)bh * Sn + q0 + wave * 32) * Dn;
    #pragma unroll
    for (int it = 0; it < 8; ++it) {
        const int idx = it * 64 + lane;     // 0..511
        const int r = idx >> 4, c = idx & 15;
        float4 f = *(float4*)(ob + r * OP + 4 * c);
        *(float4*)(op + r * Dn + 4 * c) = f;
    }
}

// ---------------- round-4 fallback (no workspace needed) -------------------
__global__ __launch_bounds__(256, 2)
void attn_fwd_mfma_r4(const float* __restrict__ Q,
                      const float* __restrict__ K,
                      const float* __restrict__ V,
                      float* __restrict__ O) {
    __shared__ __align__(16) char smem[36864];
    unsigned short* KS = (unsigned short*)smem;
    unsigned short* VT = KS + 64 * KP;
    unsigned short* PT = VT + 64 * KP;

    const int tid  = threadIdx.x;
    const int wave = tid >> 6;
    const int lane = tid & 63;
    const int l31  = lane & 31;
    const int half = lane >> 5;
    const int bh = blockIdx.x >> 4;
    const int q0 = (blockIdx.x & 15) * BM;

    const float* Qb = Q + (size_t)bh * Sn * Dn;
    const float* Kb = K + (size_t)bh * Sn * Dn;
    const float* Vb = V + (size_t)bh * Sn * Dn;
    const float FCT = 0.18033688011112042f;

    s16x8 qf[4];
    {
        const float* qp = Qb + (size_t)(q0 + wave * 32 + l31) * Dn;
        #pragma unroll
        for (int ks = 0; ks < 4; ++ks) {
            const int d0 = ks * 16 + half * 8;
            float4 f0 = *(const float4*)(qp + d0);
            float4 f1 = *(const float4*)(qp + d0 + 4);
            uint4 u;
            u.x = pack2bf(f0.x * FCT, f0.y * FCT);
            u.y = pack2bf(f0.z * FCT, f0.w * FCT);
            u.z = pack2bf(f1.x * FCT, f1.y * FCT);
            u.w = pack2bf(f1.z * FCT, f1.w * FCT);
            qf[ks] = __builtin_bit_cast(s16x8, u);
        }
    }

    f32x16 accO0, accO1;
    #pragma unroll
    for (int r = 0; r < 16; ++r) { accO0[r] = 0.f; accO1[r] = 0.f; }
    float m = -1e30f, l = 0.f;

    const int skey = tid >> 2, sdc = tid & 3;
    const int vkey = tid & 63, vdg = tid >> 6;
    unsigned short* ptw = PT + (wave * 32 + l31) * KP;

    for (int t = 0; t < NT; ++t) {
        __syncthreads();
        {
            const float* kp = Kb + (size_t)(t * BN + skey) * Dn + sdc * 16;
            unsigned short* dst = KS + skey * KP + sdc * 16;
            #pragma unroll
            for (int i = 0; i < 4; ++i) {
                float4 f = *(const float4*)(kp + 4 * i);
                uint2 w; w.x = pack2bf(f.x, f.y); w.y = pack2bf(f.z, f.w);
                *(uint2*)(dst + 4 * i) = w;
            }
        }
        {
            const float* vp = Vb + (size_t)(t * BN + vkey) * Dn + vdg * 16;
            #pragma unroll
            for (int i = 0; i < 4; ++i) {
                float4 f = *(const float4*)(vp + 4 * i);
                const int d0 = vdg * 16 + 4 * i;
                VT[(d0 + 0) * KP + vkey] = f2bf(f.x);
                VT[(d0 + 1) * KP + vkey] = f2bf(f.y);
                VT[(d0 + 2) * KP + vkey] = f2bf(f.z);
                VT[(d0 + 3) * KP + vkey] = f2bf(f.w);
            }
        }
        __syncthreads();

        f32x16 s0, s1;
        #pragma unroll
        for (int r = 0; r < 16; ++r) { s0[r] = 0.f; s1[r] = 0.f; }
        #pragma unroll
        for (int ks = 0; ks < 4; ++ks) {
            const int off = ks * 16 + half * 8;
            s16x8 kf0 = lds_frag(KS + l31 * KP + off);
            s16x8 kf1 = lds_frag(KS + (32 + l31) * KP + off);
            s0 = __builtin_amdgcn_mfma_f32_32x32x16_bf16(kf0, qf[ks], s0, 0, 0, 0);
            s1 = __builtin_amdgcn_mfma_f32_32x32x16_bf16(kf1, qf[ks], s1, 0, 0, 0);
        }

        float mx = -1e30f;
        #pragma unroll
        for (int r = 0; r < 16; ++r) mx = fmaxf(mx, fmaxf(s0[r], s1[r]));
        mx = fmaxf(mx, __shfl_xor(mx, 32, 64));
        const float mn = fmaxf(m, mx);
        const float alpha = fast_exp2(m - mn);
        m = mn;
        float rs = 0.f;
        #pragma unroll
        for (int r = 0; r < 16; ++r) {
            s0[r] = fast_exp2(s0[r] - mn); rs += s0[r];
            s1[r] = fast_exp2(s1[r] - mn); rs += s1[r];
        }
        rs += __shfl_xor(rs, 32, 64);
        l = l * alpha + rs;
        #pragma unroll
        for (int r = 0; r < 16; ++r) { accO0[r] *= alpha; accO1[r] *= alpha; }

        #pragma unroll
        for (int g = 0; g < 4; ++g) {
            uint2 w0, w1;
            w0.x = pack2bf(s0[4 * g + 0], s0[4 * g + 1]);
            w0.y = pack2bf(s0[4 * g + 2], s0[4 * g + 3]);
            w1.x = pack2bf(s1[4 * g + 0], s1[4 * g + 1]);
            w1.y = pack2bf(s1[4 * g + 2], s1[4 * g + 3]);
            *(uint2*)(ptw + 8 * g + 4 * half)      = w0;
            *(uint2*)(ptw + 8 * g + 4 * half + 32) = w1;
        }

        #pragma unroll
        for (int ks = 0; ks < 4; ++ks) {
            const int off = ks * 16 + half * 8;
            s16x8 pf  = lds_frag(ptw + off);
            s16x8 vf0 = lds_frag(VT + l31 * KP + off);
            s16x8 vf1 = lds_frag(VT + (32 + l31) * KP + off);
            accO0 = __builtin_amdgcn_mfma_f32_32x32x16_bf16(vf0, pf, accO0, 0, 0, 0);
            accO1 = __builtin_amdgcn_mfma_f32_32x32x16_bf16(vf1, pf, accO1, 0, 0, 0);
        }
    }

    __syncthreads();
    const float inv = 1.0f / l;
    float* ob = (float*)smem + wave * 32 * OP;
    #pragma unroll
    for (int g = 0; g < 4; ++g) {
        const int d0 = 8 * g + 4 * half;
        float4 f0, f1;
        f0.x = accO0[4 * g + 0] * inv; f0.y = accO0[4 * g + 1] * inv;
        f0.z = accO0[4 * g + 2] * inv; f0.w = accO0[4 * g + 3] * inv;
        f1.x = accO1[4 * g + 0] * inv; f1.y = accO1[4 * g + 1] * inv;
        f1.z = accO1[4 * g + 2] * inv; f1.w = accO1[4 * g + 3] * inv;
        *(float4*)(ob + l31 * OP + d0)      = f0;
        *(float4*)(ob + l31 * OP + d0 + 32) = f1;
    }
    float* op = O + ((size_t)bh * Sn + q0 + wave * 32) * Dn;
    #pragma unroll
    for (int it = 0; it < 8; ++it) {
        const int idx = it * 64 + lane;
        const int r = idx >> 4, c = idx & 15;
        float4 f = *(float4*)(ob + r * OP + 4 * c);
        *(float4*)(op + r * Dn + 4 * c) = f;
    }
}

extern "C" void kernel_launch(void* const* d_in, const int* in_sizes, int n_in,
                              void* d_out, int out_size, void* d_ws, size_t ws_size,
                              hipStream_t stream) {
    const float* Q = (const float*)d_in[0];
    const float* K = (const float*)d_in[1];
    const float* V = (const float*)d_in[2];
    float* O = (float*)d_out;

    const size_t elems = (size_t)Bn * Hn * Sn * Dn;      // 4M
    const size_t need  = elems * 2 * 2;                  // Kb + Vt, 16 MB

    if (ws_size >= need) {
        unsigned short* Kb = (unsigned short*)d_ws;
        unsigned short* Vt = Kb + elems;
        cast_kv<<<dim3(Bn * Hn * (Sn / 64)), dim3(256), 0, stream>>>(K, V, Kb, Vt);
        attn_fwd_mfma2<<<dim3(Bn * Hn * (Sn / BM)), dim3(256), 0, stream>>>(Q, Kb, Vt, O);
    } else {
        attn_fwd_mfma_r4<<<dim3(Bn * Hn * (Sn / BM)), dim3(256), 0, stream>>>(Q, K, V, O);
    }
}